// Round 1
// baseline (455.458 us; speedup 1.0000x reference)
//
#include <hip/hip_runtime.h>

// TranslationRotationLoss: out = mean((tp-tt)^2 over Bx3) + mean((2*acos(clip(|dot(qp_hat,qt_hat)|,0,1)))^2 over B)
// Inputs: prediction (B,7) fp32, target (B,7) fp32. Output: 1 fp32 scalar.
// Memory-bound: 448 MiB read. Each thread loads 4 rows = 7 aligned float4 per array.

__global__ __launch_bounds__(256) void trl_partial_kernel(
    const float* __restrict__ pred,
    const float* __restrict__ targ,
    float* __restrict__ partial,
    int ngroups,          // B/4
    float inv3B,          // 1/(3B)
    float invB)           // 1/B
{
    const float4* __restrict__ p4 = (const float4*)pred;
    const float4* __restrict__ t4 = (const float4*)targ;

    int tid    = blockIdx.x * blockDim.x + threadIdx.x;
    int stride = gridDim.x * blockDim.x;

    float tsum = 0.0f;  // sum of squared translation diffs (3 comps per row)
    float rsum = 0.0f;  // sum of angle^2 per row

    for (int g = tid; g < ngroups; g += stride) {
        float4 pa[7], ta[7];
        const long base = 7L * g;
#pragma unroll
        for (int k = 0; k < 7; ++k) pa[k] = p4[base + k];
#pragma unroll
        for (int k = 0; k < 7; ++k) ta[k] = t4[base + k];

        const float* pv = (const float*)pa;  // 28 floats = 4 rows of 7
        const float* tv = (const float*)ta;

#pragma unroll
        for (int j = 0; j < 4; ++j) {
            const float* p = pv + 7 * j;
            const float* t = tv + 7 * j;

            // translation: squared diff on comps 0..2
            float d0 = p[0] - t[0];
            float d1 = p[1] - t[1];
            float d2 = p[2] - t[2];
            tsum += d0 * d0 + d1 * d1 + d2 * d2;

            // rotation: geodesic angle between quaternions (comps 3..6)
            float np2 = p[3] * p[3] + p[4] * p[4] + p[5] * p[5] + p[6] * p[6];
            float nt2 = t[3] * t[3] + t[4] * t[4] + t[5] * t[5] + t[6] * t[6];
            float dot = p[3] * t[3] + p[4] * t[4] + p[5] * t[5] + p[6] * t[6];
            float c = fabsf(dot) * rsqrtf(np2 * nt2);
            c = fminf(c, 1.0f);
            float ang = 2.0f * acosf(c);
            rsum += ang * ang;
        }
    }

    // weighted combine (TRANSLATION_WEIGHT = ROTATION_WEIGHT = 1)
    float local = tsum * inv3B + rsum * invB;

    // wave (64-lane) shuffle reduce
#pragma unroll
    for (int off = 32; off > 0; off >>= 1)
        local += __shfl_down(local, off, 64);

    __shared__ float sdata[4];
    int lane = threadIdx.x & 63;
    int wave = threadIdx.x >> 6;
    if (lane == 0) sdata[wave] = local;
    __syncthreads();
    if (threadIdx.x == 0)
        partial[blockIdx.x] = sdata[0] + sdata[1] + sdata[2] + sdata[3];
}

__global__ __launch_bounds__(256) void trl_final_kernel(
    const float* __restrict__ partial, int n, float* __restrict__ out)
{
    float s = 0.0f;
    for (int i = threadIdx.x; i < n; i += 256) s += partial[i];
#pragma unroll
    for (int off = 32; off > 0; off >>= 1)
        s += __shfl_down(s, off, 64);
    __shared__ float sd[4];
    if ((threadIdx.x & 63) == 0) sd[threadIdx.x >> 6] = s;
    __syncthreads();
    if (threadIdx.x == 0) out[0] = sd[0] + sd[1] + sd[2] + sd[3];
}

extern "C" void kernel_launch(void* const* d_in, const int* in_sizes, int n_in,
                              void* d_out, int out_size, void* d_ws, size_t ws_size,
                              hipStream_t stream) {
    const float* pred = (const float*)d_in[0];
    const float* targ = (const float*)d_in[1];
    float* out = (float*)d_out;
    float* partial = (float*)d_ws;  // grid floats of scratch

    long long total = in_sizes[0];      // B * 7
    int B = (int)(total / 7);           // 8388608
    int ngroups = B / 4;                // rows processed 4-at-a-time

    float invB  = 1.0f / (float)B;
    float inv3B = invB / 3.0f;

    const int block = 256;
    const int grid  = 2048;             // each thread: 4 iterations of 4 rows

    trl_partial_kernel<<<grid, block, 0, stream>>>(pred, targ, partial, ngroups, inv3B, invB);
    trl_final_kernel<<<1, block, 0, stream>>>(partial, grid, out);
}

// Round 2
// 449.261 us; speedup vs baseline: 1.0138x; 1.0138x over previous
//
#include <hip/hip_runtime.h>

// TranslationRotationLoss: out = mean((tp-tt)^2 over Bx3) + mean((2*acos(clip(|dot(qp_hat,qt_hat)|,0,1)))^2 over B)
// Inputs: prediction (B,7) fp32, target (B,7) fp32. Output: 1 fp32 scalar.
// Memory-bound (448 MiB read). R2: coalesced global->LDS staging (1024-row tile),
// per-thread 4-row compute from LDS. Stride-28-float LDS float4 reads are
// bank-conflict-free (8 lanes tile all 32 banks).

#define TILE_F4 1792   // float4s per array per tile = 1024 rows * 7 floats / 4
#define BLOCK 256

__global__ __launch_bounds__(BLOCK) void trl_partial_kernel(
    const float* __restrict__ pred,
    const float* __restrict__ targ,
    float* __restrict__ partial,
    int ntiles,           // number of full 1024-row tiles
    int ngroups,          // B/4 (total 4-row groups)
    float inv3B,          // 1/(3B)
    float invB)           // 1/B
{
    const float4* __restrict__ p4 = (const float4*)pred;
    const float4* __restrict__ t4 = (const float4*)targ;

    __shared__ float4 sp[TILE_F4];
    __shared__ float4 st[TILE_F4];

    const int tid = threadIdx.x;

    float tsum = 0.0f;  // sum of squared translation diffs
    float rsum = 0.0f;  // sum of angle^2

    for (int tile = blockIdx.x; tile < ntiles; tile += gridDim.x) {
        const int base = tile * TILE_F4;

        // --- stage: perfectly coalesced global reads, conflict-free LDS writes ---
#pragma unroll
        for (int j = 0; j < 7; ++j) {
            const int idx = j * BLOCK + tid;
            sp[idx] = p4[base + idx];
            st[idx] = t4[base + idx];
        }
        __syncthreads();

        // --- compute: thread handles rows 4*tid .. 4*tid+3 (7 float4s, stride 28 floats) ---
        float4 pa[7], ta[7];
#pragma unroll
        for (int k = 0; k < 7; ++k) pa[k] = sp[7 * tid + k];
#pragma unroll
        for (int k = 0; k < 7; ++k) ta[k] = st[7 * tid + k];

        const float* pv = (const float*)pa;
        const float* tv = (const float*)ta;
#pragma unroll
        for (int j = 0; j < 4; ++j) {
            const float* p = pv + 7 * j;
            const float* t = tv + 7 * j;

            float d0 = p[0] - t[0];
            float d1 = p[1] - t[1];
            float d2 = p[2] - t[2];
            tsum += d0 * d0 + d1 * d1 + d2 * d2;

            float np2 = p[3] * p[3] + p[4] * p[4] + p[5] * p[5] + p[6] * p[6];
            float nt2 = t[3] * t[3] + t[4] * t[4] + t[5] * t[5] + t[6] * t[6];
            float dot = p[3] * t[3] + p[4] * t[4] + p[5] * t[5] + p[6] * t[6];
            float c = fabsf(dot) * rsqrtf(np2 * nt2);
            c = fminf(c, 1.0f);
            float ang = 2.0f * acosf(c);
            rsum += ang * ang;
        }
        __syncthreads();
    }

    // --- tail groups (if B not a multiple of 1024): block 0, old direct path ---
    if (blockIdx.x == 0) {
        for (int g = ntiles * BLOCK + tid; g < ngroups; g += BLOCK) {
            float4 pa[7], ta[7];
            const long b = 7L * g;
#pragma unroll
            for (int k = 0; k < 7; ++k) pa[k] = p4[b + k];
#pragma unroll
            for (int k = 0; k < 7; ++k) ta[k] = t4[b + k];
            const float* pv = (const float*)pa;
            const float* tv = (const float*)ta;
#pragma unroll
            for (int j = 0; j < 4; ++j) {
                const float* p = pv + 7 * j;
                const float* t = tv + 7 * j;
                float d0 = p[0] - t[0], d1 = p[1] - t[1], d2 = p[2] - t[2];
                tsum += d0 * d0 + d1 * d1 + d2 * d2;
                float np2 = p[3]*p[3] + p[4]*p[4] + p[5]*p[5] + p[6]*p[6];
                float nt2 = t[3]*t[3] + t[4]*t[4] + t[5]*t[5] + t[6]*t[6];
                float dot = p[3]*t[3] + p[4]*t[4] + p[5]*t[5] + p[6]*t[6];
                float c = fminf(fabsf(dot) * rsqrtf(np2 * nt2), 1.0f);
                float ang = 2.0f * acosf(c);
                rsum += ang * ang;
            }
        }
    }

    float local = tsum * inv3B + rsum * invB;

#pragma unroll
    for (int off = 32; off > 0; off >>= 1)
        local += __shfl_down(local, off, 64);

    __shared__ float sdata[4];
    int lane = threadIdx.x & 63;
    int wave = threadIdx.x >> 6;
    if (lane == 0) sdata[wave] = local;
    __syncthreads();
    if (threadIdx.x == 0)
        partial[blockIdx.x] = sdata[0] + sdata[1] + sdata[2] + sdata[3];
}

__global__ __launch_bounds__(256) void trl_final_kernel(
    const float* __restrict__ partial, int n, float* __restrict__ out)
{
    float s = 0.0f;
    for (int i = threadIdx.x; i < n; i += 256) s += partial[i];
#pragma unroll
    for (int off = 32; off > 0; off >>= 1)
        s += __shfl_down(s, off, 64);
    __shared__ float sd[4];
    if ((threadIdx.x & 63) == 0) sd[threadIdx.x >> 6] = s;
    __syncthreads();
    if (threadIdx.x == 0) out[0] = sd[0] + sd[1] + sd[2] + sd[3];
}

extern "C" void kernel_launch(void* const* d_in, const int* in_sizes, int n_in,
                              void* d_out, int out_size, void* d_ws, size_t ws_size,
                              hipStream_t stream) {
    const float* pred = (const float*)d_in[0];
    const float* targ = (const float*)d_in[1];
    float* out = (float*)d_out;
    float* partial = (float*)d_ws;

    long long total = in_sizes[0];      // B * 7
    int B = (int)(total / 7);           // 8388608
    int ngroups = B / 4;                // 4-row groups
    int ntiles = ngroups / BLOCK;       // full 1024-row tiles (8192 for B=8388608)

    float invB  = 1.0f / (float)B;
    float inv3B = invB / 3.0f;

    const int grid = 2048;              // grid-stride over 8192 tiles, 4 tiles/block

    trl_partial_kernel<<<grid, BLOCK, 0, stream>>>(pred, targ, partial, ntiles, ngroups, inv3B, invB);
    trl_final_kernel<<<1, BLOCK, 0, stream>>>(partial, grid, out);
}